// Round 21
// baseline (802.572 us; speedup 1.0000x reference)
//
#include <hip/hip_runtime.h>

#define N_NODES 50000
#define N_EDGES 800000
#define D 128
#define H 16
#define DH 512

typedef __attribute__((ext_vector_type(8))) short short8;
typedef __attribute__((ext_vector_type(4))) float f32x4;

static __device__ __forceinline__ unsigned short f2bf(float f) {
    unsigned u = __float_as_uint(f);
    u += 0x7FFF + ((u >> 16) & 1);   // round-to-nearest-even
    return (unsigned short)(u >> 16);
}
static __device__ __forceinline__ float bf2f(unsigned short u) {
    return __uint_as_float(((unsigned)u) << 16);
}

// ---------------- LayerNorm (f32 in -> bf16 out), one wave per row ----------------
__global__ void ln_kernel(const float* __restrict__ x, const float* __restrict__ g,
                          const float* __restrict__ b, unsigned short* __restrict__ out, int n) {
    int w = (blockIdx.x * blockDim.x + threadIdx.x) >> 6;
    int lane = threadIdx.x & 63;
    if (w >= n) return;
    float2 v = *(const float2*)(x + (size_t)w * D + lane * 2);
    float s = v.x + v.y, ss = v.x * v.x + v.y * v.y;
#pragma unroll
    for (int off = 32; off; off >>= 1) { s += __shfl_xor(s, off); ss += __shfl_xor(ss, off); }
    float mean = s * (1.0f / D);
    float var = ss * (1.0f / D) - mean * mean;
    float rstd = rsqrtf(var + 1e-5f);
    float2 gv = *(const float2*)(g + lane * 2);
    float2 bv = *(const float2*)(b + lane * 2);
    ushort2 o;
    o.x = f2bf((v.x - mean) * rstd * gv.x + bv.x);
    o.y = f2bf((v.y - mean) * rstd * gv.y + bv.y);
    *(ushort2*)(out + (size_t)w * D + lane * 2) = o;
}

// ---------------- fused weight prep: all transposes + bias concat in ONE launch ----------------
__global__ void prep_kernel(const float* __restrict__ wq, const float* __restrict__ wk,
                            const float* __restrict__ wv, const float* __restrict__ ws,
                            const float* __restrict__ we, const float* __restrict__ wp,
                            const float* __restrict__ w1, const float* __restrict__ w2,
                            const float* __restrict__ bq, const float* __restrict__ bk,
                            const float* __restrict__ bv, const float* __restrict__ bs,
                            unsigned short* __restrict__ wqkvsT, unsigned short* __restrict__ weT,
                            unsigned short* __restrict__ wpT, unsigned short* __restrict__ w1T,
                            unsigned short* __restrict__ w2T, float* __restrict__ bias_qkvs) {
    int idx = blockIdx.x * blockDim.x + threadIdx.x;
    if (idx < 65536) {                       // wq|wk|wv|ws -> wqkvsT [512][128]
        int seg = idx >> 14, r = idx & 16383;
        const float* src = seg == 0 ? wq : seg == 1 ? wk : seg == 2 ? wv : ws;
        int o = r >> 7, i = r & 127;
        wqkvsT[idx] = f2bf(src[i * 128 + o]);
    } else if (idx < 81920) {                // weT [128][128]
        int r = idx - 65536; int o = r >> 7, i = r & 127;
        weT[r] = f2bf(we[i * 128 + o]);
    } else if (idx < 98304) {                // wpT [128][128]
        int r = idx - 81920; int o = r >> 7, i = r & 127;
        wpT[r] = f2bf(wp[i * 128 + o]);
    } else if (idx < 163840) {               // w1T [512][128], src w1 [128][512]
        int r = idx - 98304; int o = r >> 7, i = r & 127;
        w1T[r] = f2bf(w1[i * 512 + o]);
    } else if (idx < 229376) {               // w2T [128][512], src w2 [512][128]
        int r = idx - 163840; int o = r >> 9, i = r & 511;
        w2T[r] = f2bf(w2[i * 128 + o]);
    } else if (idx < 229888) {               // bias concat
        int r = idx - 229376;
        const float* p = r < 128 ? bq : r < 256 ? bk : r < 384 ? bv : bs;
        bias_qkvs[r] = p[r & 127];
    }
}

// ---------------- CSR build ----------------
__global__ void hist_kernel(const int* __restrict__ edge_index, int* __restrict__ counts) {
    int e = blockIdx.x * blockDim.x + threadIdx.x;
    if (e < N_EDGES) atomicAdd(&counts[edge_index[N_EDGES + e]], 1);
}

__global__ void scan1_kernel(const int* __restrict__ counts, int* __restrict__ excl,
                             int* __restrict__ bsum) {
    __shared__ int sm[1024];
    int b = blockIdx.x, tid = threadIdx.x;
    int idx = b * 1024 + tid;
    int v = (idx < N_NODES) ? counts[idx] : 0;
    sm[tid] = v;
    __syncthreads();
    for (int off = 1; off < 1024; off <<= 1) {
        int t = (tid >= off) ? sm[tid - off] : 0;
        __syncthreads();
        sm[tid] += t;
        __syncthreads();
    }
    if (idx < N_NODES) excl[idx] = sm[tid] - v;
    if (tid == 1023) bsum[b] = sm[1023];
}

__global__ void scan2_kernel(int* __restrict__ bsum, int nb) {
    if (threadIdx.x == 0 && blockIdx.x == 0) {
        int run = 0;
        for (int i = 0; i < nb; ++i) { int v = bsum[i]; bsum[i] = run; run += v; }
    }
}

__global__ void scan3_kernel(const int* __restrict__ excl, const int* __restrict__ bsum,
                             int* __restrict__ row_ptr, int* __restrict__ cursor) {
    int b = blockIdx.x, tid = threadIdx.x;
    int idx = b * 1024 + tid;
    if (idx < N_NODES) {
        int v = bsum[b] + excl[idx];
        row_ptr[idx] = v;
        cursor[idx] = v;
    }
    if (idx == 0) row_ptr[N_NODES] = N_EDGES;
}

__global__ void scatter_kernel(const int* __restrict__ edge_index, int* __restrict__ cursor,
                               int* __restrict__ slot_of, int* __restrict__ src_ord) {
    int e = blockIdx.x * blockDim.x + threadIdx.x;
    if (e < N_EDGES) {
        int dst = edge_index[N_EDGES + e];
        int pos = atomicAdd(&cursor[dst], 1);
        slot_of[e] = pos;
        src_ord[pos] = edge_index[e];
    }
}

// ---------------- generic bf16 MFMA GEMM ----------------
enum { EPI_F32 = 0, EPI_RESID = 1, EPI_SILU_BF = 2, EPI_ADDOUT = 3, EPI_BF16 = 4, EPI_QKVS = 5 };

template <int KD, int EPI>
__global__ void gemm_kernel(const unsigned short* __restrict__ A, const unsigned short* __restrict__ BT,
                            const float* __restrict__ bias, void* __restrict__ outp,
                            const float* __restrict__ extra, int M, int Nout) {
    int wave = threadIdx.x >> 6, lane = threadIdx.x & 63;
    int lr = lane & 15, lq = lane >> 4;
    int row0 = (blockIdx.x * 4 + wave) * 16;
    int col0 = blockIdx.y * 64;
    int arow = row0 + lr;
    if (arow >= M) arow = M - 1;
    f32x4 z = {0.f, 0.f, 0.f, 0.f};
    f32x4 acc[4] = {z, z, z, z};
#pragma unroll
    for (int t = 0; t < KD / 32; ++t) {
        short8 a = *(const short8*)(A + (size_t)arow * KD + t * 32 + lq * 8);
#pragma unroll
        for (int cf = 0; cf < 4; ++cf) {
            short8 b = *(const short8*)(BT + (size_t)(col0 + cf * 16 + lr) * KD + t * 32 + lq * 8);
            acc[cf] = __builtin_amdgcn_mfma_f32_16x16x32_bf16(a, b, acc[cf], 0, 0, 0);
        }
    }
#pragma unroll
    for (int cf = 0; cf < 4; ++cf) {
        int col = col0 + cf * 16 + lr;
        float bv = bias[col];
#pragma unroll
        for (int r = 0; r < 4; ++r) {
            int row = row0 + lq * 4 + r;
            if (row >= M) continue;
            float v = acc[cf][r] + bv;
            if (EPI == EPI_F32) {
                ((float*)outp)[(size_t)row * Nout + col] = v;
            } else if (EPI == EPI_RESID) {
                ((float*)outp)[(size_t)row * Nout + col] = v + extra[(size_t)row * D + col];
            } else if (EPI == EPI_SILU_BF) {
                float sg = 1.0f / (1.0f + __expf(-v));
                ((unsigned short*)outp)[(size_t)row * Nout + col] = f2bf(v * sg);
            } else if (EPI == EPI_ADDOUT) {
                ((float*)outp)[(size_t)row * Nout + col] = v + extra[(size_t)row * D + col];
            } else if (EPI == EPI_QKVS) {
                // q | kv-interleaved | xr: q c->c, k c->128+2c, v c->129+2c, xr c->384+c
                int seg = col >> 7, c = col & 127;
                size_t o = (seg == 0) ? (size_t)c : (seg == 1) ? (size_t)(128 + 2 * c)
                         : (seg == 2) ? (size_t)(129 + 2 * c) : (size_t)(384 + c);
                ((unsigned short*)outp)[(size_t)row * 512 + o] = f2bf(v);
            } else {  // EPI_BF16
                ((unsigned short*)outp)[(size_t)row * Nout + col] = f2bf(v);
            }
        }
    }
}

// ---------------- fused edge GEMM + q.(E+be) partial score ----------------
// 8-tile chunk per block, TWO-BUFFER (A/B) software pipeline, fully unrolled:
// loads for tile j+2 are issued inside compute(j) right after j's registers are
// consumed -> ~1.7 tiles of latency cover (depth-1 gave ~1). All 8 tiles'
// indices fetched in 4 packed coalesced loads at the prologue (lane-packed 4
// tiles/reg, shfl-extracted). Prefetch distance stays 32-64 edges (16-32KB) —
// per-tile cache footprint unchanged (R8 locality lesson).
#define ES_CHUNK 8
#define ES_NTILE (N_EDGES / 32)              // 25000 (divisible by 8)
#define ES_GRID (ES_NTILE / ES_CHUNK)        // 3125

#define ES_LOAD(ATTR, QREG, J)                                                           \
    do {                                                                                 \
        int e0w_ = (t0 + (J)) * 32 + w16;                                                \
        _Pragma("unroll")                                                                \
        for (int t_ = 0; t_ < 4; ++t_) {                                                 \
            const f32x4* p_ = (const f32x4*)(edge_attr + (size_t)(e0w_ + lr) * D + t_ * 32 + lq * 8); \
            ATTR[2 * t_]     = __builtin_nontemporal_load(p_);                           \
            ATTR[2 * t_ + 1] = __builtin_nontemporal_load(p_ + 1);                       \
        }                                                                                \
        int dsrc_ = ((J) < 4) ? dstP0 : dstP1;                                           \
        _Pragma("unroll")                                                                \
        for (int it_ = 0; it_ < 8; ++it_) {                                              \
            int dst_ = __shfl(dsrc_, (((J) & 3) << 4) + it_ * 2 + plane);                \
            QREG[it_] = *(const ushort4*)(qkvs + (size_t)dst_ * 512 + h2 * 4);           \
        }                                                                                \
    } while (0)

#define ES_COMPUTE(ATTR, QREG, J, PF)                                                    \
    do {                                                                                 \
        _Pragma("unroll")                                                                \
        for (int it_ = 0; it_ < 8; ++it_)                                                \
            *(ushort4*)(&q_lds[w16 + it_ * 2 + plane][h2 * 4]) = QREG[it_];              \
        short8 a_[4];                                                                    \
        _Pragma("unroll")                                                                \
        for (int t_ = 0; t_ < 4; ++t_) {                                                 \
            f32x4 lo_ = ATTR[2 * t_], hi_ = ATTR[2 * t_ + 1];                            \
            short8 av_;                                                                  \
            av_[0] = f2bf(lo_[0]); av_[1] = f2bf(lo_[1]);                                \
            av_[2] = f2bf(lo_[2]); av_[3] = f2bf(lo_[3]);                                \
            av_[4] = f2bf(hi_[0]); av_[5] = f2bf(hi_[1]);                                \
            av_[6] = f2bf(hi_[2]); av_[7] = f2bf(hi_[3]);                                \
            a_[t_] = av_;                                                                \
        }                                                                                \
        PF;                                                                              \
        f32x4 z_ = {0.f, 0.f, 0.f, 0.f};                                                 \
        f32x4 acc_[8] = {z_, z_, z_, z_, z_, z_, z_, z_};                                \
        _Pragma("unroll")                                                                \
        for (int cf_ = 0; cf_ < 8; ++cf_) {                                              \
            _Pragma("unroll")                                                            \
            for (int t_ = 0; t_ < 4; ++t_) {                                             \
                short8 b_ = *(const short8*)(weT + (size_t)(cf_ * 16 + lr) * D + t_ * 32 + lq * 8); \
                acc_[cf_] = __builtin_amdgcn_mfma_f32_16x16x32_bf16(b_, a_[t_], acc_[cf_], 0, 0, 0); \
            }                                                                            \
        }                                                                                \
        _Pragma("unroll")                                                                \
        for (int cf_ = 0; cf_ < 8; ++cf_) {                                              \
            int ch_ = cf_ * 16 + lq * 4;                                                 \
            ushort4 q4_ = *(const ushort4*)(&q_lds[w16 + lr][ch_]);                      \
            f32x4 be4_ = *(const f32x4*)(be + ch_);                                      \
            float p_ = bf2f(q4_.x) * (acc_[cf_][0] + be4_[0])                            \
                     + bf2f(q4_.y) * (acc_[cf_][1] + be4_[1])                            \
                     + bf2f(q4_.z) * (acc_[cf_][2] + be4_[2])                            \
                     + bf2f(q4_.w) * (acc_[cf_][3] + be4_[3]);                           \
            p_ += __shfl_xor(p_, 16);                                                    \
            if ((lq & 1) == 0)                                                           \
                s_lds[w16 + lr][cf_ * 2 + (lq >> 1)] = p_;                               \
        }                                                                                \
        int ssrc_ = ((J) < 4) ? slotP0 : slotP1;                                         \
        int el16_ = lane >> 2;                                                           \
        int slot_ = __shfl(ssrc_, (((J) & 3) << 4) + el16_);                             \
        f32x4 sv_ = *(const f32x4*)(&s_lds[w16 + el16_][(lane & 3) * 4]);                \
        ushort4 o_;                                                                      \
        o_.x = f2bf(sv_[0]); o_.y = f2bf(sv_[1]); o_.z = f2bf(sv_[2]); o_.w = f2bf(sv_[3]); \
        *(ushort4*)(qE16 + (size_t)slot_ * 16 + (lane & 3) * 4) = o_;                    \
    } while (0)

__global__ __launch_bounds__(128)
void edge_score_kernel(const float* __restrict__ edge_attr,
                       const unsigned short* __restrict__ weT,
                       const float* __restrict__ be, const int* __restrict__ edge_index,
                       const int* __restrict__ slot_of,
                       const unsigned short* __restrict__ qkvs,
                       unsigned short* __restrict__ qE16) {
    __shared__ unsigned short q_lds[32][132];
    __shared__ float s_lds[32][20];
    int wave = threadIdx.x >> 6, lane = threadIdx.x & 63;
    int lr = lane & 15, lq = lane >> 4;
    int w16 = wave * 16;
    int plane = lane >> 5, h2 = lane & 31;
    int t0 = blockIdx.x * ES_CHUNK;

    // packed index prologue: 4 coalesced loads cover all 8 tiles
    // lanes (j*16 + e) hold tile t0+j (P0) / t0+4+j (P1), edge e of this wave's slice
    int tg = lane >> 4, te = lane & 15;
    int dstP0 = edge_index[N_EDGES + (t0 + tg) * 32 + w16 + te];
    int slotP0 = slot_of[(t0 + tg) * 32 + w16 + te];
    int dstP1 = edge_index[N_EDGES + (t0 + 4 + tg) * 32 + w16 + te];
    int slotP1 = slot_of[(t0 + 4 + tg) * 32 + w16 + te];

    f32x4 attrA[8], attrB[8];
    ushort4 qregA[8], qregB[8];
    ES_LOAD(attrA, qregA, 0);
    ES_LOAD(attrB, qregB, 1);

    ES_COMPUTE(attrA, qregA, 0, ES_LOAD(attrA, qregA, 2));
    ES_COMPUTE(attrB, qregB, 1, ES_LOAD(attrB, qregB, 3));
    ES_COMPUTE(attrA, qregA, 2, ES_LOAD(attrA, qregA, 4));
    ES_COMPUTE(attrB, qregB, 3, ES_LOAD(attrB, qregB, 5));
    ES_COMPUTE(attrA, qregA, 4, ES_LOAD(attrA, qregA, 6));
    ES_COMPUTE(attrB, qregB, 5, ES_LOAD(attrB, qregB, 7));
    ES_COMPUTE(attrA, qregA, 6, );
    ES_COMPUTE(attrB, qregB, 7, );
}

// ---------------- aggregation: one wave per node, PERSISTENT; kv in ONE ushort4 gather ----------------
#define AGG_GRID 2048
__global__ void agg_kernel(const int* __restrict__ row_ptr, const int* __restrict__ src_ord,
                           const unsigned short* __restrict__ qE16, const unsigned short* __restrict__ qkvs,
                           unsigned short* __restrict__ aggxr) {
    int lane = threadIdx.x & 63;
    int c = lane * 2, h = lane >> 2;
    const float scale = 0.35355339059327373f;  // 1/sqrt(8)
    int nw = (AGG_GRID * 256) >> 6;
    for (int w = (int)((blockIdx.x * blockDim.x + threadIdx.x) >> 6); w < N_NODES; w += nw) {
        int s = row_ptr[w], e = row_ptr[w + 1], deg = e - s;
        int src_p = (lane < deg) ? src_ord[s + lane] : 0;
        ushort2 q2 = *(const ushort2*)(qkvs + (size_t)w * 512 + c);
        float qa = bf2f(q2.x), qb = bf2f(q2.y);
        float acc0 = 0.f, acc1 = 0.f, den = 0.f;
        for (int i = 0; i < deg; ++i) {
            int src = (i < 64) ? __shfl(src_p, i) : src_ord[s + i];
            ushort4 kv = *(const ushort4*)(qkvs + (size_t)src * 512 + 128 + (size_t)c * 2);
            float pa = qa * bf2f(kv.x) + qb * bf2f(kv.z);
            pa += __shfl_xor(pa, 1);
            pa += __shfl_xor(pa, 2);
            float qEv = bf2f(qE16[(size_t)(s + i) * 16 + h]);
            float ex = __expf((pa + qEv) * scale);
            acc0 += ex * bf2f(kv.y);
            acc1 += ex * bf2f(kv.w);
            den += ex;
        }
        float inv = den > 0.f ? 1.0f / den : 0.f;
        ushort2 x2 = *(const ushort2*)(qkvs + (size_t)w * 512 + 384 + c);
        ushort2 o;
        o.x = f2bf(acc0 * inv + bf2f(x2.x));
        o.y = f2bf(acc1 * inv + bf2f(x2.y));
        *(ushort2*)(aggxr + (size_t)w * D + c) = o;
    }
}

extern "C" void kernel_launch(void* const* d_in, const int* in_sizes, int n_in,
                              void* d_out, int out_size, void* d_ws, size_t ws_size,
                              hipStream_t stream) {
    const float* x = (const float*)d_in[0];
    const int* edge_index = (const int*)d_in[1];
    const float* edge_attr = (const float*)d_in[2];
    const float* ln1_g = (const float*)d_in[3];
    const float* ln1_b = (const float*)d_in[4];
    const float* wq = (const float*)d_in[5];  const float* bq = (const float*)d_in[6];
    const float* wk = (const float*)d_in[7];  const float* bk = (const float*)d_in[8];
    const float* wv = (const float*)d_in[9];  const float* bv = (const float*)d_in[10];
    const float* wsw = (const float*)d_in[11]; const float* bs = (const float*)d_in[12];
    const float* we = (const float*)d_in[13]; const float* be = (const float*)d_in[14];
    const float* wp = (const float*)d_in[15]; const float* bp = (const float*)d_in[16];
    const float* mlp_g = (const float*)d_in[17]; const float* mlp_b = (const float*)d_in[18];
    const float* w1 = (const float*)d_in[19]; const float* b1 = (const float*)d_in[20];
    const float* w2 = (const float*)d_in[21]; const float* b2 = (const float*)d_in[22];

    char* base = (char*)d_ws;
    size_t off = 0;
    auto alloc = [&](size_t bytes) -> char* {
        char* p = base + off;
        off = (off + bytes + 255) & ~(size_t)255;
        return p;
    };
    unsigned short* qkvs   = (unsigned short*)alloc((size_t)N_NODES * 512 * 2);  // q | kv-interleaved | xr
    unsigned short* qE16   = (unsigned short*)alloc((size_t)N_EDGES * H * 2);
    unsigned short* h_bf   = (unsigned short*)alloc((size_t)N_NODES * D * 2);
    unsigned short* aggxr  = (unsigned short*)alloc((size_t)N_NODES * D * 2);
    float* outbuf          = (float*)alloc((size_t)N_NODES * D * 4);
    unsigned short* ln2_bf = (unsigned short*)alloc((size_t)N_NODES * D * 2);
    unsigned short* silu_bf= (unsigned short*)alloc((size_t)N_NODES * DH * 2);
    int* counts            = (int*)alloc((size_t)N_NODES * 4);
    int* row_ptr           = (int*)alloc((size_t)(N_NODES + 1) * 4);
    int* cursor            = (int*)alloc((size_t)N_NODES * 4);
    int* slot_of           = (int*)alloc((size_t)N_EDGES * 4);
    int* src_ord           = (int*)alloc((size_t)N_EDGES * 4);
    int* excl              = (int*)alloc((size_t)N_NODES * 4);
    int* bsum              = (int*)alloc(64 * 4);
    unsigned short* wqkvsT = (unsigned short*)alloc(512 * 128 * 2);
    unsigned short* weT    = (unsigned short*)alloc(128 * 128 * 2);
    unsigned short* wpT    = (unsigned short*)alloc(128 * 128 * 2);
    unsigned short* w1T    = (unsigned short*)alloc(512 * 128 * 2);
    unsigned short* w2T    = (unsigned short*)alloc(128 * 512 * 2);
    float* bias_qkvs       = (float*)alloc(512 * 4);

    const int NB = (N_NODES + 1023) / 1024;  // 49

    // ---- weight prep (single launch) ----
    prep_kernel<<<898, 256, 0, stream>>>(wq, wk, wv, wsw, we, wp, w1, w2, bq, bk, bv, bs,
                                         wqkvsT, weT, wpT, w1T, w2T, bias_qkvs);

    // ---- CSR by dst (parallel scan) ----
    (void)hipMemsetAsync(counts, 0, (size_t)N_NODES * 4, stream);
    hist_kernel<<<(N_EDGES + 255) / 256, 256, 0, stream>>>(edge_index, counts);
    scan1_kernel<<<NB, 1024, 0, stream>>>(counts, excl, bsum);
    scan2_kernel<<<1, 64, 0, stream>>>(bsum, NB);
    scan3_kernel<<<NB, 1024, 0, stream>>>(excl, bsum, row_ptr, cursor);
    scatter_kernel<<<(N_EDGES + 255) / 256, 256, 0, stream>>>(edge_index, cursor, slot_of, src_ord);

    // ---- node pipeline ----
    ln_kernel<<<(N_NODES + 3) / 4, 256, 0, stream>>>(x, ln1_g, ln1_b, h_bf, N_NODES);

    dim3 g_node((N_NODES + 63) / 64, 8);
    gemm_kernel<128, EPI_QKVS><<<g_node, 256, 0, stream>>>(h_bf, wqkvsT, bias_qkvs, qkvs, nullptr, N_NODES, 512);

    edge_score_kernel<<<ES_GRID, 128, 0, stream>>>(edge_attr, weT, be, edge_index, slot_of, qkvs, qE16);

    agg_kernel<<<AGG_GRID, 256, 0, stream>>>(row_ptr, src_ord, qE16, qkvs, aggxr);

    dim3 g_out((N_NODES + 63) / 64, 2);
    gemm_kernel<128, EPI_RESID><<<g_out, 256, 0, stream>>>(aggxr, wpT, bp, outbuf, x, N_NODES, 128);

    ln_kernel<<<(N_NODES + 3) / 4, 256, 0, stream>>>(outbuf, mlp_g, mlp_b, ln2_bf, N_NODES);

    dim3 g_mlp1((N_NODES + 63) / 64, 8);
    gemm_kernel<128, EPI_SILU_BF><<<g_mlp1, 256, 0, stream>>>(ln2_bf, w1T, b1, silu_bf, nullptr, N_NODES, 512);

    dim3 g_mlp2((N_NODES + 63) / 64, 2);
    gemm_kernel<512, EPI_ADDOUT><<<g_mlp2, 256, 0, stream>>>(silu_bf, w2T, b2, (float*)d_out, outbuf, N_NODES, 128);
}

// Round 22
// 556.124 us; speedup vs baseline: 1.4432x; 1.4432x over previous
//
#include <hip/hip_runtime.h>

#define N_NODES 50000
#define N_EDGES 800000
#define D 128
#define H 16
#define DH 512

typedef __attribute__((ext_vector_type(8))) short short8;
typedef __attribute__((ext_vector_type(4))) float f32x4;

static __device__ __forceinline__ unsigned short f2bf(float f) {
    unsigned u = __float_as_uint(f);
    u += 0x7FFF + ((u >> 16) & 1);   // round-to-nearest-even
    return (unsigned short)(u >> 16);
}
static __device__ __forceinline__ float bf2f(unsigned short u) {
    return __uint_as_float(((unsigned)u) << 16);
}

// ---------------- LayerNorm (f32 in -> bf16 out), one wave per row ----------------
__global__ void ln_kernel(const float* __restrict__ x, const float* __restrict__ g,
                          const float* __restrict__ b, unsigned short* __restrict__ out, int n) {
    int w = (blockIdx.x * blockDim.x + threadIdx.x) >> 6;
    int lane = threadIdx.x & 63;
    if (w >= n) return;
    float2 v = *(const float2*)(x + (size_t)w * D + lane * 2);
    float s = v.x + v.y, ss = v.x * v.x + v.y * v.y;
#pragma unroll
    for (int off = 32; off; off >>= 1) { s += __shfl_xor(s, off); ss += __shfl_xor(ss, off); }
    float mean = s * (1.0f / D);
    float var = ss * (1.0f / D) - mean * mean;
    float rstd = rsqrtf(var + 1e-5f);
    float2 gv = *(const float2*)(g + lane * 2);
    float2 bv = *(const float2*)(b + lane * 2);
    ushort2 o;
    o.x = f2bf((v.x - mean) * rstd * gv.x + bv.x);
    o.y = f2bf((v.y - mean) * rstd * gv.y + bv.y);
    *(ushort2*)(out + (size_t)w * D + lane * 2) = o;
}

// ---------------- fused weight prep: all transposes + bias concat in ONE launch ----------------
__global__ void prep_kernel(const float* __restrict__ wq, const float* __restrict__ wk,
                            const float* __restrict__ wv, const float* __restrict__ ws,
                            const float* __restrict__ we, const float* __restrict__ wp,
                            const float* __restrict__ w1, const float* __restrict__ w2,
                            const float* __restrict__ bq, const float* __restrict__ bk,
                            const float* __restrict__ bv, const float* __restrict__ bs,
                            unsigned short* __restrict__ wqkvsT, unsigned short* __restrict__ weT,
                            unsigned short* __restrict__ wpT, unsigned short* __restrict__ w1T,
                            unsigned short* __restrict__ w2T, float* __restrict__ bias_qkvs) {
    int idx = blockIdx.x * blockDim.x + threadIdx.x;
    if (idx < 65536) {                       // wq|wk|wv|ws -> wqkvsT [512][128]
        int seg = idx >> 14, r = idx & 16383;
        const float* src = seg == 0 ? wq : seg == 1 ? wk : seg == 2 ? wv : ws;
        int o = r >> 7, i = r & 127;
        wqkvsT[idx] = f2bf(src[i * 128 + o]);
    } else if (idx < 81920) {                // weT [128][128]
        int r = idx - 65536; int o = r >> 7, i = r & 127;
        weT[r] = f2bf(we[i * 128 + o]);
    } else if (idx < 98304) {                // wpT [128][128]
        int r = idx - 81920; int o = r >> 7, i = r & 127;
        wpT[r] = f2bf(wp[i * 128 + o]);
    } else if (idx < 163840) {               // w1T [512][128], src w1 [128][512]
        int r = idx - 98304; int o = r >> 7, i = r & 127;
        w1T[r] = f2bf(w1[i * 512 + o]);
    } else if (idx < 229376) {               // w2T [128][512], src w2 [512][128]
        int r = idx - 163840; int o = r >> 9, i = r & 511;
        w2T[r] = f2bf(w2[i * 128 + o]);
    } else if (idx < 229888) {               // bias concat
        int r = idx - 229376;
        const float* p = r < 128 ? bq : r < 256 ? bk : r < 384 ? bv : bs;
        bias_qkvs[r] = p[r & 127];
    }
}

// ---------------- CSR build ----------------
__global__ void hist_kernel(const int* __restrict__ edge_index, int* __restrict__ counts) {
    int e = blockIdx.x * blockDim.x + threadIdx.x;
    if (e < N_EDGES) atomicAdd(&counts[edge_index[N_EDGES + e]], 1);
}

__global__ void scan1_kernel(const int* __restrict__ counts, int* __restrict__ excl,
                             int* __restrict__ bsum) {
    __shared__ int sm[1024];
    int b = blockIdx.x, tid = threadIdx.x;
    int idx = b * 1024 + tid;
    int v = (idx < N_NODES) ? counts[idx] : 0;
    sm[tid] = v;
    __syncthreads();
    for (int off = 1; off < 1024; off <<= 1) {
        int t = (tid >= off) ? sm[tid - off] : 0;
        __syncthreads();
        sm[tid] += t;
        __syncthreads();
    }
    if (idx < N_NODES) excl[idx] = sm[tid] - v;
    if (tid == 1023) bsum[b] = sm[1023];
}

__global__ void scan2_kernel(int* __restrict__ bsum, int nb) {
    if (threadIdx.x == 0 && blockIdx.x == 0) {
        int run = 0;
        for (int i = 0; i < nb; ++i) { int v = bsum[i]; bsum[i] = run; run += v; }
    }
}

__global__ void scan3_kernel(const int* __restrict__ excl, const int* __restrict__ bsum,
                             int* __restrict__ row_ptr, int* __restrict__ cursor) {
    int b = blockIdx.x, tid = threadIdx.x;
    int idx = b * 1024 + tid;
    if (idx < N_NODES) {
        int v = bsum[b] + excl[idx];
        row_ptr[idx] = v;
        cursor[idx] = v;
    }
    if (idx == 0) row_ptr[N_NODES] = N_EDGES;
}

__global__ void scatter_kernel(const int* __restrict__ edge_index, int* __restrict__ cursor,
                               int* __restrict__ slot_of, int* __restrict__ src_ord) {
    int e = blockIdx.x * blockDim.x + threadIdx.x;
    if (e < N_EDGES) {
        int dst = edge_index[N_EDGES + e];
        int pos = atomicAdd(&cursor[dst], 1);
        slot_of[e] = pos;
        src_ord[pos] = edge_index[e];
    }
}

// ---------------- generic bf16 MFMA GEMM ----------------
enum { EPI_F32 = 0, EPI_RESID = 1, EPI_SILU_BF = 2, EPI_ADDOUT = 3, EPI_BF16 = 4, EPI_QKVS = 5 };

template <int KD, int EPI>
__global__ void gemm_kernel(const unsigned short* __restrict__ A, const unsigned short* __restrict__ BT,
                            const float* __restrict__ bias, void* __restrict__ outp,
                            const float* __restrict__ extra, int M, int Nout) {
    int wave = threadIdx.x >> 6, lane = threadIdx.x & 63;
    int lr = lane & 15, lq = lane >> 4;
    int row0 = (blockIdx.x * 4 + wave) * 16;
    int col0 = blockIdx.y * 64;
    int arow = row0 + lr;
    if (arow >= M) arow = M - 1;
    f32x4 z = {0.f, 0.f, 0.f, 0.f};
    f32x4 acc[4] = {z, z, z, z};
#pragma unroll
    for (int t = 0; t < KD / 32; ++t) {
        short8 a = *(const short8*)(A + (size_t)arow * KD + t * 32 + lq * 8);
#pragma unroll
        for (int cf = 0; cf < 4; ++cf) {
            short8 b = *(const short8*)(BT + (size_t)(col0 + cf * 16 + lr) * KD + t * 32 + lq * 8);
            acc[cf] = __builtin_amdgcn_mfma_f32_16x16x32_bf16(a, b, acc[cf], 0, 0, 0);
        }
    }
#pragma unroll
    for (int cf = 0; cf < 4; ++cf) {
        int col = col0 + cf * 16 + lr;
        float bv = bias[col];
#pragma unroll
        for (int r = 0; r < 4; ++r) {
            int row = row0 + lq * 4 + r;
            if (row >= M) continue;
            float v = acc[cf][r] + bv;
            if (EPI == EPI_F32) {
                ((float*)outp)[(size_t)row * Nout + col] = v;
            } else if (EPI == EPI_RESID) {
                ((float*)outp)[(size_t)row * Nout + col] = v + extra[(size_t)row * D + col];
            } else if (EPI == EPI_SILU_BF) {
                float sg = 1.0f / (1.0f + __expf(-v));
                ((unsigned short*)outp)[(size_t)row * Nout + col] = f2bf(v * sg);
            } else if (EPI == EPI_ADDOUT) {
                ((float*)outp)[(size_t)row * Nout + col] = v + extra[(size_t)row * D + col];
            } else if (EPI == EPI_QKVS) {
                // q | kv-interleaved | xr: q c->c, k c->128+2c, v c->129+2c, xr c->384+c
                int seg = col >> 7, c = col & 127;
                size_t o = (seg == 0) ? (size_t)c : (seg == 1) ? (size_t)(128 + 2 * c)
                         : (seg == 2) ? (size_t)(129 + 2 * c) : (size_t)(384 + c);
                ((unsigned short*)outp)[(size_t)row * 512 + o] = f2bf(v);
            } else {  // EPI_BF16
                ((unsigned short*)outp)[(size_t)row * Nout + col] = f2bf(v);
            }
        }
    }
}

// ---------------- fused edge GEMM + q.(E+be) partial score ----------------
// R20 structure (best measured): contiguous-chunk persistent blocks, depth-1
// pipeline, rolling single-buffer state (VGPR-light -> occupancy preserved;
// R21's depth-2 unroll collapsed occupancy 44%->10% and regressed 2.5x).
// Refinements: (a) q-gathers issued BEFORE attr NT-loads, so next tile's LDS
// commit can proceed at vmcnt(8) while attr loads stay in flight; (b) chunk 10
// (30% fewer exposed prologues).
#define ES_CHUNK 10
#define ES_NTILE (N_EDGES / 32)                 // 25000
#define ES_GRID (ES_NTILE / ES_CHUNK)           // 2500
__global__ __launch_bounds__(128)
void edge_score_kernel(const float* __restrict__ edge_attr,
                       const unsigned short* __restrict__ weT,
                       const float* __restrict__ be, const int* __restrict__ edge_index,
                       const int* __restrict__ slot_of,
                       const unsigned short* __restrict__ qkvs,
                       unsigned short* __restrict__ qE16) {
    __shared__ unsigned short q_lds[32][132];
    __shared__ float s_lds[32][20];
    int wave = threadIdx.x >> 6, lane = threadIdx.x & 63;
    int lr = lane & 15, lq = lane >> 4;
    int w16 = wave * 16;
    int plane = lane >> 5, h2 = lane & 31;

    int t0 = blockIdx.x * ES_CHUNK;
    int tend = t0 + ES_CHUNK;

    // -------- prologue: tile t0 state + tile t0+1 indices --------
    int e0w = t0 * 32 + w16;
    int dstv = edge_index[N_EDGES + e0w + lr];
    int slotv = slot_of[e0w + lr];
    ushort4 qreg[8];
#pragma unroll
    for (int it = 0; it < 8; ++it) {
        int dst = __shfl(dstv, it * 2 + plane);
        qreg[it] = *(const ushort4*)(qkvs + (size_t)dst * 512 + h2 * 4);
    }
    f32x4 attrf[8];
#pragma unroll
    for (int t = 0; t < 4; ++t) {
        const f32x4* p = (const f32x4*)(edge_attr + (size_t)(e0w + lr) * D + t * 32 + lq * 8);
        attrf[2 * t]     = __builtin_nontemporal_load(p);
        attrf[2 * t + 1] = __builtin_nontemporal_load(p + 1);
    }
    int dstv_n = 0, slotv_n = 0;
    if (t0 + 1 < tend) {
        int e1w = (t0 + 1) * 32 + w16;
        dstv_n = edge_index[N_EDGES + e1w + lr];
        slotv_n = slot_of[e1w + lr];
    }

    for (int tile = t0; tile < tend; ++tile) {
        // 1) commit current q rows to wave-private LDS (q-gathers were issued
        //    before attr loads -> compiler may wait at vmcnt(8), attr in flight)
#pragma unroll
        for (int it = 0; it < 8; ++it)
            *(ushort4*)(&q_lds[w16 + it * 2 + plane][h2 * 4]) = qreg[it];

        // 2) convert current attr to bf16 A-frags
        short8 a[4];
#pragma unroll
        for (int t = 0; t < 4; ++t) {
            f32x4 lo = attrf[2 * t], hi = attrf[2 * t + 1];
            short8 av;
            av[0] = f2bf(lo[0]); av[1] = f2bf(lo[1]); av[2] = f2bf(lo[2]); av[3] = f2bf(lo[3]);
            av[4] = f2bf(hi[0]); av[5] = f2bf(hi[1]); av[6] = f2bf(hi[2]); av[7] = f2bf(hi[3]);
            a[t] = av;
        }
        int slot_cur = slotv;

        // 3) issue next tile's q-gathers FIRST, then attr NT-loads (+32 edges)
        if (tile + 1 < tend) {
            int e1w = (tile + 1) * 32 + w16;
#pragma unroll
            for (int it = 0; it < 8; ++it) {
                int dst = __shfl(dstv_n, it * 2 + plane);
                qreg[it] = *(const ushort4*)(qkvs + (size_t)dst * 512 + h2 * 4);
            }
#pragma unroll
            for (int t = 0; t < 4; ++t) {
                const f32x4* p = (const f32x4*)(edge_attr + (size_t)(e1w + lr) * D + t * 32 + lq * 8);
                attrf[2 * t]     = __builtin_nontemporal_load(p);
                attrf[2 * t + 1] = __builtin_nontemporal_load(p + 1);
            }
        }
        dstv = dstv_n; slotv = slotv_n;
        // 4) indices for tile+2
        if (tile + 2 < tend) {
            int e2w = (tile + 2) * 32 + w16;
            dstv_n = edge_index[N_EDGES + e2w + lr];
            slotv_n = slot_of[e2w + lr];
        }

        // 5) E^T via swapped operands: D[m=outcol within cf][n=edge]
        f32x4 z = {0.f, 0.f, 0.f, 0.f};
        f32x4 acc[8] = {z, z, z, z, z, z, z, z};
#pragma unroll
        for (int cf = 0; cf < 8; ++cf) {
#pragma unroll
            for (int t = 0; t < 4; ++t) {
                short8 b = *(const short8*)(weT + (size_t)(cf * 16 + lr) * D + t * 32 + lq * 8);
                acc[cf] = __builtin_amdgcn_mfma_f32_16x16x32_bf16(b, a[t], acc[cf], 0, 0, 0);
            }
        }

        // 6) score: lane(lq,lr) holds E[ch = cf*16+lq*4+r][edge = lr]
#pragma unroll
        for (int cf = 0; cf < 8; ++cf) {
            int ch = cf * 16 + lq * 4;
            ushort4 q4 = *(const ushort4*)(&q_lds[w16 + lr][ch]);
            f32x4 be4 = *(const f32x4*)(be + ch);
            float p = bf2f(q4.x) * (acc[cf][0] + be4[0])
                    + bf2f(q4.y) * (acc[cf][1] + be4[1])
                    + bf2f(q4.z) * (acc[cf][2] + be4[2])
                    + bf2f(q4.w) * (acc[cf][3] + be4[3]);
            p += __shfl_xor(p, 16);
            if ((lq & 1) == 0)
                s_lds[w16 + lr][cf * 2 + (lq >> 1)] = p;
        }

        // 7) CSR-slot-ordered bf16 store (32B per edge)
        int el16 = lane >> 2;
        int slot = __shfl(slot_cur, el16);
        f32x4 sv = *(const f32x4*)(&s_lds[w16 + el16][(lane & 3) * 4]);
        ushort4 o;
        o.x = f2bf(sv[0]); o.y = f2bf(sv[1]); o.z = f2bf(sv[2]); o.w = f2bf(sv[3]);
        *(ushort4*)(qE16 + (size_t)slot * 16 + (lane & 3) * 4) = o;
    }
}

// ---------------- aggregation: one wave per node, PERSISTENT; kv in ONE ushort4 gather ----------------
#define AGG_GRID 2048
__global__ void agg_kernel(const int* __restrict__ row_ptr, const int* __restrict__ src_ord,
                           const unsigned short* __restrict__ qE16, const unsigned short* __restrict__ qkvs,
                           unsigned short* __restrict__ aggxr) {
    int lane = threadIdx.x & 63;
    int c = lane * 2, h = lane >> 2;
    const float scale = 0.35355339059327373f;  // 1/sqrt(8)
    int nw = (AGG_GRID * 256) >> 6;
    for (int w = (int)((blockIdx.x * blockDim.x + threadIdx.x) >> 6); w < N_NODES; w += nw) {
        int s = row_ptr[w], e = row_ptr[w + 1], deg = e - s;
        int src_p = (lane < deg) ? src_ord[s + lane] : 0;
        ushort2 q2 = *(const ushort2*)(qkvs + (size_t)w * 512 + c);
        float qa = bf2f(q2.x), qb = bf2f(q2.y);
        float acc0 = 0.f, acc1 = 0.f, den = 0.f;
        for (int i = 0; i < deg; ++i) {
            int src = (i < 64) ? __shfl(src_p, i) : src_ord[s + i];
            ushort4 kv = *(const ushort4*)(qkvs + (size_t)src * 512 + 128 + (size_t)c * 2);
            float pa = qa * bf2f(kv.x) + qb * bf2f(kv.z);
            pa += __shfl_xor(pa, 1);
            pa += __shfl_xor(pa, 2);
            float qEv = bf2f(qE16[(size_t)(s + i) * 16 + h]);
            float ex = __expf((pa + qEv) * scale);
            acc0 += ex * bf2f(kv.y);
            acc1 += ex * bf2f(kv.w);
            den += ex;
        }
        float inv = den > 0.f ? 1.0f / den : 0.f;
        ushort2 x2 = *(const ushort2*)(qkvs + (size_t)w * 512 + 384 + c);
        ushort2 o;
        o.x = f2bf(acc0 * inv + bf2f(x2.x));
        o.y = f2bf(acc1 * inv + bf2f(x2.y));
        *(ushort2*)(aggxr + (size_t)w * D + c) = o;
    }
}

extern "C" void kernel_launch(void* const* d_in, const int* in_sizes, int n_in,
                              void* d_out, int out_size, void* d_ws, size_t ws_size,
                              hipStream_t stream) {
    const float* x = (const float*)d_in[0];
    const int* edge_index = (const int*)d_in[1];
    const float* edge_attr = (const float*)d_in[2];
    const float* ln1_g = (const float*)d_in[3];
    const float* ln1_b = (const float*)d_in[4];
    const float* wq = (const float*)d_in[5];  const float* bq = (const float*)d_in[6];
    const float* wk = (const float*)d_in[7];  const float* bk = (const float*)d_in[8];
    const float* wv = (const float*)d_in[9];  const float* bv = (const float*)d_in[10];
    const float* wsw = (const float*)d_in[11]; const float* bs = (const float*)d_in[12];
    const float* we = (const float*)d_in[13]; const float* be = (const float*)d_in[14];
    const float* wp = (const float*)d_in[15]; const float* bp = (const float*)d_in[16];
    const float* mlp_g = (const float*)d_in[17]; const float* mlp_b = (const float*)d_in[18];
    const float* w1 = (const float*)d_in[19]; const float* b1 = (const float*)d_in[20];
    const float* w2 = (const float*)d_in[21]; const float* b2 = (const float*)d_in[22];

    char* base = (char*)d_ws;
    size_t off = 0;
    auto alloc = [&](size_t bytes) -> char* {
        char* p = base + off;
        off = (off + bytes + 255) & ~(size_t)255;
        return p;
    };
    unsigned short* qkvs   = (unsigned short*)alloc((size_t)N_NODES * 512 * 2);  // q | kv-interleaved | xr
    unsigned short* qE16   = (unsigned short*)alloc((size_t)N_EDGES * H * 2);
    unsigned short* h_bf   = (unsigned short*)alloc((size_t)N_NODES * D * 2);
    unsigned short* aggxr  = (unsigned short*)alloc((size_t)N_NODES * D * 2);
    float* outbuf          = (float*)alloc((size_t)N_NODES * D * 4);
    unsigned short* ln2_bf = (unsigned short*)alloc((size_t)N_NODES * D * 2);
    unsigned short* silu_bf= (unsigned short*)alloc((size_t)N_NODES * DH * 2);
    int* counts            = (int*)alloc((size_t)N_NODES * 4);
    int* row_ptr           = (int*)alloc((size_t)(N_NODES + 1) * 4);
    int* cursor            = (int*)alloc((size_t)N_NODES * 4);
    int* slot_of           = (int*)alloc((size_t)N_EDGES * 4);
    int* src_ord           = (int*)alloc((size_t)N_EDGES * 4);
    int* excl              = (int*)alloc((size_t)N_NODES * 4);
    int* bsum              = (int*)alloc(64 * 4);
    unsigned short* wqkvsT = (unsigned short*)alloc(512 * 128 * 2);
    unsigned short* weT    = (unsigned short*)alloc(128 * 128 * 2);
    unsigned short* wpT    = (unsigned short*)alloc(128 * 128 * 2);
    unsigned short* w1T    = (unsigned short*)alloc(512 * 128 * 2);
    unsigned short* w2T    = (unsigned short*)alloc(128 * 512 * 2);
    float* bias_qkvs       = (float*)alloc(512 * 4);

    const int NB = (N_NODES + 1023) / 1024;  // 49

    // ---- weight prep (single launch) ----
    prep_kernel<<<898, 256, 0, stream>>>(wq, wk, wv, wsw, we, wp, w1, w2, bq, bk, bv, bs,
                                         wqkvsT, weT, wpT, w1T, w2T, bias_qkvs);

    // ---- CSR by dst (parallel scan) ----
    (void)hipMemsetAsync(counts, 0, (size_t)N_NODES * 4, stream);
    hist_kernel<<<(N_EDGES + 255) / 256, 256, 0, stream>>>(edge_index, counts);
    scan1_kernel<<<NB, 1024, 0, stream>>>(counts, excl, bsum);
    scan2_kernel<<<1, 64, 0, stream>>>(bsum, NB);
    scan3_kernel<<<NB, 1024, 0, stream>>>(excl, bsum, row_ptr, cursor);
    scatter_kernel<<<(N_EDGES + 255) / 256, 256, 0, stream>>>(edge_index, cursor, slot_of, src_ord);

    // ---- node pipeline ----
    ln_kernel<<<(N_NODES + 3) / 4, 256, 0, stream>>>(x, ln1_g, ln1_b, h_bf, N_NODES);

    dim3 g_node((N_NODES + 63) / 64, 8);
    gemm_kernel<128, EPI_QKVS><<<g_node, 256, 0, stream>>>(h_bf, wqkvsT, bias_qkvs, qkvs, nullptr, N_NODES, 512);

    edge_score_kernel<<<ES_GRID, 128, 0, stream>>>(edge_attr, weT, be, edge_index, slot_of, qkvs, qE16);

    agg_kernel<<<AGG_GRID, 256, 0, stream>>>(row_ptr, src_ord, qE16, qkvs, aggxr);

    dim3 g_out((N_NODES + 63) / 64, 2);
    gemm_kernel<128, EPI_RESID><<<g_out, 256, 0, stream>>>(aggxr, wpT, bp, outbuf, x, N_NODES, 128);

    ln_kernel<<<(N_NODES + 3) / 4, 256, 0, stream>>>(outbuf, mlp_g, mlp_b, ln2_bf, N_NODES);

    dim3 g_mlp1((N_NODES + 63) / 64, 8);
    gemm_kernel<128, EPI_SILU_BF><<<g_mlp1, 256, 0, stream>>>(ln2_bf, w1T, b1, silu_bf, nullptr, N_NODES, 512);

    dim3 g_mlp2((N_NODES + 63) / 64, 2);
    gemm_kernel<512, EPI_ADDOUT><<<g_mlp2, 256, 0, stream>>>(silu_bf, w2T, b2, (float*)d_out, outbuf, N_NODES, 128);
}